// Round 6
// baseline (111.430 us; speedup 1.0000x reference)
//
#include <hip/hip_runtime.h>
#include <hip/hip_bf16.h>

typedef unsigned short u16;
typedef unsigned int u32;
typedef __bf16 bf16x8 __attribute__((ext_vector_type(8)));
typedef float f32x4 __attribute__((ext_vector_type(4)));

#define DD 768
#define LN_EPS 1e-5f

__device__ __forceinline__ u16 f2bf(float f) {
  union { float f; unsigned u; } x; x.f = f;
  unsigned r = x.u + 0x7fffu + ((x.u >> 16) & 1u);
  return (u16)(r >> 16);
}
__device__ __forceinline__ float bf2f(u16 h) {
  union { unsigned u; float f; } x; x.u = ((unsigned)h) << 16; return x.f;
}

__device__ __forceinline__ void async16(void* ldsp, const void* g) {
  __builtin_amdgcn_global_load_lds(
      (const __attribute__((address_space(1))) void*)g,
      (__attribute__((address_space(3))) void*)ldsp,
      16, 0, 0);
}

// 8 f32 -> 8 bf16 (RNE, v_cvt_pk_bf16_f32) -> one 16B LDS write
__device__ __forceinline__ void cvt_write16(void* dst, float4 a, float4 b) {
  __hip_bfloat162 p0 = __float22bfloat162_rn(float2{a.x, a.y});
  __hip_bfloat162 p1 = __float22bfloat162_rn(float2{a.z, a.w});
  __hip_bfloat162 p2 = __float22bfloat162_rn(float2{b.x, b.y});
  __hip_bfloat162 p3 = __float22bfloat162_rn(float2{b.z, b.w});
  uint4 v;
  v.x = *reinterpret_cast<u32*>(&p0);
  v.y = *reinterpret_cast<u32*>(&p1);
  v.z = *reinterpret_cast<u32*>(&p2);
  v.w = *reinterpret_cast<u32*>(&p3);
  *reinterpret_cast<uint4*>(dst) = v;
}

// ---------------------------------------------------------------------------
// 128x128 2-phase GEMM (proven round-2 structure), optional cast-in-stage A.
// CASTA=0: A is bf16, staged via global_load_lds (source pre-swizzled).
// CASTA=1: A is f32; 8x dwordx4 -> regs issued BEFORE compute (latency hidden
//          under MFMA), then cvt_pk -> swizzled ds_write_b128 AFTER compute
//          into the next buffer. Same XOR swizzle as the ds_read side.
// MODE 0: out bf16 raw; MODE 1: bf16 acc+bias(+f32 R); MODE 2: bf16 relu;
// MODE 3: f32 relu.
// ---------------------------------------------------------------------------
template<int MODE, int CASTA>
__device__ __forceinline__ void gemm_body(
    const void* __restrict__ Aptr, const u16* __restrict__ W,
    const float* __restrict__ bias, const float* __restrict__ Rf,
    void* __restrict__ Out, int M, int N, int K)
{
  const u16*   Abf = (const u16*)Aptr;
  const float* Af  = (const float*)Aptr;
  __shared__ char lds[65536];
  const int tid  = threadIdx.x;
  const int lane = tid & 63;
  const int wid  = tid >> 6;
  const int wm = wid >> 1, wn = wid & 1;
  const int row0 = blockIdx.x * 128;
  const int col0 = blockIdx.y * 128;
  const int l15 = lane & 15;
  const int l4  = lane >> 4;

  f32x4 acc[4][4];
  const f32x4 zero4 = {0.f, 0.f, 0.f, 0.f};
#pragma unroll
  for (int m = 0; m < 4; ++m)
#pragma unroll
    for (int n = 0; n < 4; ++n) acc[m][n] = zero4;

  int aoff[2][4], boff[2][4];
#pragma unroll
  for (int ks = 0; ks < 2; ++ks) {
#pragma unroll
    for (int m = 0; m < 4; ++m) {
      int ra = wm * 64 + m * 16 + l15;
      aoff[ks][m] = ra * 128 + (((ks * 4 + l4) ^ (ra & 7)) * 16);
      int rb = wn * 64 + m * 16 + l15;
      boff[ks][m] = 16384 + rb * 128 + (((ks * 4 + l4) ^ (rb & 7)) * 16);
    }
  }

  const int srow = tid >> 3;             // 0..31
  const int scb  = tid & 7;              // 16B chunk 0..7
  int rr[4], cbp[4];
#pragma unroll
  for (int c = 0; c < 4; ++c) {
    rr[c]  = srow + c * 32;
    cbp[c] = (scb ^ (rr[c] & 7)) * 8;    // swizzled chunk (elem offset)
  }
  const size_t abase = (size_t)row0 * K;
  const size_t wbase = (size_t)col0 * K;

  float4 Ra[8];                          // f32 A prefetch regs (CASTA)

  auto LOADR = [&](int kt) {             // issue 8 dwordx4, no wait here
#pragma unroll
    for (int c = 0; c < 4; ++c) {
      const float* src = Af + abase + (size_t)rr[c] * K + kt + scb * 8;
      Ra[2 * c]     = *(const float4*)(src);
      Ra[2 * c + 1] = *(const float4*)(src + 4);
    }
  };
  auto WRITEA = [&](int buf) {           // cvt + swizzled ds_write_b128
#pragma unroll
    for (int c = 0; c < 4; ++c)
      cvt_write16(lds + buf * 32768 + rr[c] * 128 + cbp[c] * 2,
                  Ra[2 * c], Ra[2 * c + 1]);
  };
  auto STAGE_A = [&](int buf, int kt) {  // bf16 path: async, pre-swizzled src
    char* bA = lds + buf * 32768 + wid * 1024;
#pragma unroll
    for (int c = 0; c < 4; ++c)
      async16(bA + c * 4096, Abf + abase + (size_t)rr[c] * K + kt + cbp[c]);
  };
  auto STAGE_W = [&](int buf, int kt) {
    char* bB = lds + buf * 32768 + 16384 + wid * 1024;
#pragma unroll
    for (int c = 0; c < 4; ++c)
      async16(bB + c * 4096, W + wbase + (size_t)rr[c] * K + kt + cbp[c]);
  };
  auto COMPUTE = [&](int buf) {
    const char* base = lds + buf * 32768;
#pragma unroll
    for (int ks = 0; ks < 2; ++ks) {
      bf16x8 af[4], bfr[4];
#pragma unroll
      for (int m = 0; m < 4; ++m) af[m]  = *(const bf16x8*)(base + aoff[ks][m]);
#pragma unroll
      for (int n = 0; n < 4; ++n) bfr[n] = *(const bf16x8*)(base + boff[ks][n]);
      __builtin_amdgcn_s_setprio(1);
#pragma unroll
      for (int m = 0; m < 4; ++m)
#pragma unroll
        for (int n = 0; n < 4; ++n)
          acc[m][n] = __builtin_amdgcn_mfma_f32_16x16x32_bf16(
              af[m], bfr[n], acc[m][n], 0, 0, 0);
      __builtin_amdgcn_s_setprio(0);
    }
  };

  if (CASTA) LOADR(0);
  STAGE_W(0, 0);
  if (!CASTA) STAGE_A(0, 0);
  if (CASTA) WRITEA(0);
  __syncthreads();
  int cur = 0;
  for (int kt = 64; kt < K; kt += 64) {
    if (CASTA) LOADR(kt);        // next-tile f32 loads in flight
    STAGE_W(cur ^ 1, kt);        // next-tile W async loads in flight
    if (!CASTA) STAGE_A(cur ^ 1, kt);
    COMPUTE(cur);                // hides LOADR latency
    if (CASTA) WRITEA(cur ^ 1);  // WAR-safe: buf cur^1 last read 1 barrier ago
    __syncthreads();             // drains vmcnt + lgkmcnt: next tile ready
    cur ^= 1;
  }
  COMPUTE(cur);

  float bcol[4];
#pragma unroll
  for (int n = 0; n < 4; ++n)
    bcol[n] = (MODE == 0) ? 0.f : bias[col0 + wn * 64 + n * 16 + l15];

#pragma unroll
  for (int m = 0; m < 4; ++m) {
    int r0 = row0 + wm * 64 + m * 16 + l4 * 4;
#pragma unroll
    for (int n = 0; n < 4; ++n) {
      int c = col0 + wn * 64 + n * 16 + l15;
#pragma unroll
      for (int j = 0; j < 4; ++j) {
        size_t idx = (size_t)(r0 + j) * N + c;
        float v = acc[m][n][j];
        if (MODE == 0) {
          ((u16*)Out)[idx] = f2bf(v);
        } else if (MODE == 1) {
          v += bcol[n];
          if (Rf) v += Rf[idx];
          ((u16*)Out)[idx] = f2bf(v);
        } else if (MODE == 2) {
          ((u16*)Out)[idx] = f2bf(fmaxf(v + bcol[n], 0.f));
        } else {
          ((float*)Out)[idx] = fmaxf(v + bcol[n], 0.f);
        }
      }
    }
  }
}

__global__ __launch_bounds__(256) void k_gemm_fuse(
    const float* WoSa, const u16* WvTSa, u16* WsaF,
    const float* WoCa, const u16* WvTCa, u16* WcaF)
{
  int z = blockIdx.z;
  gemm_body<0, 1>(z ? (const void*)WoCa : (const void*)WoSa,
                  z ? WvTCa : WvTSa, nullptr, nullptr,
                  z ? WcaF : WsaF, DD, DD, DD);
}

__global__ __launch_bounds__(256) void k_gemm_att(
    const float* query, const float* ref,
    const u16* WsaF, const u16* WcaF,
    const float* bsa, const float* bca,
    u16* t1, u16* ca, int M)
{
  int z = blockIdx.z;
  gemm_body<1, 1>(z ? (const void*)ref : (const void*)query,
                  z ? WcaF : WsaF, z ? bca : bsa,
                  z ? (const float*)nullptr : query,
                  z ? (void*)ca : (void*)t1, M, DD, DD);
}

__global__ __launch_bounds__(256) void k_mlp1(
    const u16* xb, const u16* W1, const float* b1, u16* hb, int M)
{ gemm_body<2, 0>(xb, W1, b1, nullptr, hb, M, DD, DD); }

__global__ __launch_bounds__(256) void k_mlp2(
    const u16* hb, const u16* W2, const float* b2, float* out, int M)
{ gemm_body<3, 0>(hb, W2, b2, nullptr, out, M, 512, DD); }

// ---------------------------------------------------------------------------
// Prep kernel (weights only now): [0,1152) transpose-cast Wv x2;
// [1152,1536) fused bias x2; [1536,...) grid-stride cast of W1, W2.
// query/ref casts eliminated (att does cast-in-stage from f32).
// ---------------------------------------------------------------------------
__global__ __launch_bounds__(256) void k_prep(
    const float* sa_w_v, u16* WvTSaB, const float* ca_w_v, u16* WvTCaB,
    const float* WoSa, const float* bvSa, const float* boSa, float* bsaF,
    const float* WoCa, const float* bvCa, const float* boCa, float* bcaF,
    const float* s0, u16* d0, int n0, const float* s1, u16* d1, int n1)
{
  __shared__ float t[32][33];
  const int b = blockIdx.x;
  const int tid = threadIdx.x;

  if (b < 1152) {            // transpose-cast: dst[k][t] = bf16(src[t][k])
    int z = b / 576, r = b % 576;
    const float* src = z ? ca_w_v : sa_w_v;
    u16* dst = z ? WvTCaB : WvTSaB;
    int by = (r / 24) * 32, bx = (r % 24) * 32;
    int x = tid & 31, y4 = tid >> 5;
#pragma unroll
    for (int i = 0; i < 32; i += 8)
      t[y4 + i][x] = src[(size_t)(by + y4 + i) * DD + bx + x];
    __syncthreads();
#pragma unroll
    for (int i = 0; i < 32; i += 8)
      dst[(size_t)(bx + y4 + i) * DD + by + x] = f2bf(t[x][y4 + i]);
    return;
  }
  if (b < 1536) {            // bias: out[n] = dot(Wo[n,:], bv) + bo[n]
    int bb = b - 1152;
    const float *Wo, *bv, *bo; float* out;
    if (bb < 192) { Wo = WoSa; bv = bvSa; bo = boSa; out = bsaF; }
    else          { Wo = WoCa; bv = bvCa; bo = boCa; out = bcaF; bb -= 192; }
    int lane = tid & 63;
    int n = bb * 4 + (tid >> 6);
    float s = 0.f;
    for (int k = lane; k < DD; k += 64) s += Wo[(size_t)n * DD + k] * bv[k];
#pragma unroll
    for (int o = 32; o > 0; o >>= 1) s += __shfl_down(s, o, 64);
    if (lane == 0) out[n] = s + bo[n];
    return;
  }
  // cast W1, W2 (float4 -> ushort4)
  int total = n0 + n1;
  int nblk = gridDim.x - 1536;
  for (int i = (b - 1536) * 256 + tid; i < total; i += nblk * 256) {
    int j = i; const float* s; u16* d;
    if (j < n0) { s = s0; d = d0; }
    else        { j -= n0; s = s1; d = d1; }
    float4 v = ((const float4*)s)[j];
    ushort4 o;
    o.x = f2bf(v.x); o.y = f2bf(v.y); o.z = f2bf(v.z); o.w = f2bf(v.w);
    ((ushort4*)d)[j] = o;
  }
}

// ---------------------------------------------------------------------------
// Double LayerNorm: q = LN1(t1); y = q + ca; x = relu(LN2(y)) -> bf16
// ---------------------------------------------------------------------------
__global__ __launch_bounds__(256) void k_ln(
    const u16* __restrict__ t1, const u16* __restrict__ caB,
    const float* __restrict__ g1, const float* __restrict__ b1,
    const float* __restrict__ g2, const float* __restrict__ b2,
    u16* __restrict__ xout, int M)
{
  int row = blockIdx.x * 4 + (threadIdx.x >> 6);
  int lane = threadIdx.x & 63;
  const ushort4* p1 = (const ushort4*)(t1 + (size_t)row * DD);
  const ushort4* pc = (const ushort4*)(caB + (size_t)row * DD);
  const float4* pg1 = (const float4*)g1; const float4* pb1 = (const float4*)b1;
  const float4* pg2 = (const float4*)g2; const float4* pb2 = (const float4*)b2;

  float v[12];
  float s = 0.f, s2 = 0.f;
#pragma unroll
  for (int i = 0; i < 3; ++i) {
    ushort4 q = p1[lane + 64 * i];
    float a0 = bf2f(q.x), a1 = bf2f(q.y), a2 = bf2f(q.z), a3 = bf2f(q.w);
    v[i*4+0] = a0; v[i*4+1] = a1; v[i*4+2] = a2; v[i*4+3] = a3;
    s  += a0 + a1 + a2 + a3;
    s2 += a0*a0 + a1*a1 + a2*a2 + a3*a3;
  }
#pragma unroll
  for (int o = 32; o > 0; o >>= 1) { s += __shfl_xor(s, o, 64); s2 += __shfl_xor(s2, o, 64); }
  float mu = s * (1.f / DD);
  float rs = rsqrtf(s2 * (1.f / DD) - mu * mu + LN_EPS);

  float y[12];
  s = 0.f; s2 = 0.f;
#pragma unroll
  for (int i = 0; i < 3; ++i) {
    float4 gg = pg1[lane + 64 * i]; float4 bb = pb1[lane + 64 * i];
    ushort4 cc = pc[lane + 64 * i];
    float y0 = (v[i*4+0] - mu) * rs * gg.x + bb.x + bf2f(cc.x);
    float y1 = (v[i*4+1] - mu) * rs * gg.y + bb.y + bf2f(cc.y);
    float y2 = (v[i*4+2] - mu) * rs * gg.z + bb.z + bf2f(cc.z);
    float y3 = (v[i*4+3] - mu) * rs * gg.w + bb.w + bf2f(cc.w);
    y[i*4+0] = y0; y[i*4+1] = y1; y[i*4+2] = y2; y[i*4+3] = y3;
    s  += y0 + y1 + y2 + y3;
    s2 += y0*y0 + y1*y1 + y2*y2 + y3*y3;
  }
#pragma unroll
  for (int o = 32; o > 0; o >>= 1) { s += __shfl_xor(s, o, 64); s2 += __shfl_xor(s2, o, 64); }
  float mu2 = s * (1.f / DD);
  float rs2 = rsqrtf(s2 * (1.f / DD) - mu2 * mu2 + LN_EPS);

  ushort4* po = (ushort4*)(xout + (size_t)row * DD);
#pragma unroll
  for (int i = 0; i < 3; ++i) {
    float4 gg = pg2[lane + 64 * i]; float4 bb = pb2[lane + 64 * i];
    ushort4 o;
    o.x = f2bf(fmaxf((y[i*4+0] - mu2) * rs2 * gg.x + bb.x, 0.f));
    o.y = f2bf(fmaxf((y[i*4+1] - mu2) * rs2 * gg.y + bb.y, 0.f));
    o.z = f2bf(fmaxf((y[i*4+2] - mu2) * rs2 * gg.z + bb.z, 0.f));
    o.w = f2bf(fmaxf((y[i*4+3] - mu2) * rs2 * gg.w + bb.w, 0.f));
    po[lane + 64 * i] = o;
  }
}

// ---------------------------------------------------------------------------
extern "C" void kernel_launch(void* const* d_in, const int* in_sizes, int n_in,
                              void* d_out, int out_size, void* d_ws, size_t ws_size,
                              hipStream_t stream) {
  const float* query    = (const float*)d_in[0];
  const float* ref      = (const float*)d_in[1];
  const float* sa_w_in  = (const float*)d_in[2];
  const float* sa_b_in  = (const float*)d_in[3];
  const float* sa_w_out = (const float*)d_in[4];
  const float* sa_b_out = (const float*)d_in[5];
  const float* ln1_g    = (const float*)d_in[6];
  const float* ln1_b    = (const float*)d_in[7];
  const float* ca_w_in  = (const float*)d_in[8];
  const float* ca_b_in  = (const float*)d_in[9];
  const float* ca_w_out = (const float*)d_in[10];
  const float* ca_b_out = (const float*)d_in[11];
  const float* ln2_g    = (const float*)d_in[12];
  const float* ln2_b    = (const float*)d_in[13];
  const float* w1       = (const float*)d_in[14];
  const float* b1       = (const float*)d_in[15];
  const float* w2       = (const float*)d_in[16];
  const float* b2       = (const float*)d_in[17];
  const int M = in_sizes[0] / DD;   // 8192

  char* p = (char*)d_ws;
  u16* h_bf  = (u16*)p; p += (size_t)M * DD * 2;   // mlp1 out
  u16* x_bf  = (u16*)p; p += (size_t)M * DD * 2;   // ln out
  u16* t1    = (u16*)p; p += (size_t)M * DD * 2;
  u16* ca    = (u16*)p; p += (size_t)M * DD * 2;
  u16* WvTSaB = (u16*)p; p += DD * DD * 2;
  u16* WvTCaB = (u16*)p; p += DD * DD * 2;
  u16* W1b    = (u16*)p; p += DD * DD * 2;
  u16* W2b    = (u16*)p; p += 512 * DD * 2;
  u16* WsaF   = (u16*)p; p += DD * DD * 2;
  u16* WcaF   = (u16*)p; p += DD * DD * 2;
  float* bsaF = (float*)p; p += DD * 4;
  float* bcaF = (float*)p; p += DD * 4;

  const int nw  = DD * DD / 4;
  const int nw2 = 512 * DD / 4;

  k_prep<<<dim3(1536 + 960), 256, 0, stream>>>(
      sa_w_in + 2 * DD * DD, WvTSaB, ca_w_in + 2 * DD * DD, WvTCaB,
      sa_w_out, sa_b_in + 2 * DD, sa_b_out, bsaF,
      ca_w_out, ca_b_in + 2 * DD, ca_b_out, bcaF,
      w1, W1b, nw, w2, W2b, nw2);

  k_gemm_fuse<<<dim3(6, 6, 2), 256, 0, stream>>>(
      sa_w_out, WvTSaB, WsaF, ca_w_out, WvTCaB, WcaF);

  k_gemm_att<<<dim3(M / 128, 6, 2), 256, 0, stream>>>(
      query, ref, WsaF, WcaF, bsaF, bcaF, t1, ca, M);

  k_ln<<<dim3(M / 4), 256, 0, stream>>>(
      t1, ca, ln1_g, ln1_b, ln2_g, ln2_b, x_bf, M);

  k_mlp1<<<dim3(M / 128, 6), 256, 0, stream>>>(x_bf, W1b, b1, h_bf, M);

  k_mlp2<<<dim3(M / 128, 4), 256, 0, stream>>>(h_bf, W2b, b2, (float*)d_out, M);
}